// Round 13
// baseline (685.392 us; speedup 1.0000x reference)
//
#include <hip/hip_runtime.h>
#include <hip/hip_bf16.h>

// GlobalAttention (general): B=32, T=512, S=1024, D=1024, f32 in/out.
// Split-bf16 GEMMs, round-13 = round-12 engine with the B-read addressing
// fix (bRd no longer double-adds the 16384 plane base; r12 read past the
// buffer -> NaN). 128x128 tile, 256 threads (4 waves, 2Mx2N, per-wave
// 64x64), chunk planes {Ah,Al,Bh[,Bl]} of 128r x 32c staged once per
// K-chunk; 2 phases/chunk:
//   ph1: read Ah,Bh -> MM(Ah,Bh)            [16 MFMA]
//   ph2: read Bl,Al -> MM(Ah,Bl); MM(al,Bh) [32 MFMA; Ah,Bh stay in regs]
// (2-term: ph1 MM(Ah,Bh) / ph2 read Al, MM(Al,Bh)).
// LDS 64KB (3-term) / 48KB (2-term) -> 2 blocks/CU: INDEPENDENT barrier
// domains per CU so one block's MFMAs cover the other's read-latency head.
// Stage ledger (re-audited with outstanding-load queue walk):
//   entering c.ph1 outstanding = {Ah,Bh}(c+1);
//   ph1 stages {Al,Bl}(c+1) [3-term] / Al(c+1) [2-term]; VM4/VM2 drains
//   {Ah,Bh}(c+1) (read c+1.ph1, published c.ph2 barrier);
//   ph2 stages {Ah,Bh}(c+2); VM4 drains {Al,Bl}(c+1) (read c+1.ph2,
//   published c+1.ph1 barrier). Every overwrite >=1 barrier after its
//   region's reads drain (A/B LDS reads all drain at their phase's MM).
// Peel: (NC-2).ph1 stages last Al[/Bl] then VM0. Swizzle: phys 16B-granule
// g = logical ^ ((row>>1)&3) via pre-swizzled global source + swizzled
// ds_read. XCD decode (batched): 1024 blocks, each XCD owns 4 batches.

typedef short bf16x8 __attribute__((ext_vector_type(8)));
typedef float f32x4 __attribute__((ext_vector_type(4)));
typedef unsigned short us;

#define NB 32
#define NT_ 512
#define NS 1024
#define ND 1024

__device__ inline us f2bf(float x) {
  unsigned u = __float_as_uint(x);
  u += 0x7FFFu + ((u >> 16) & 1u);
  return (us)(u >> 16);
}
__device__ inline float bf2f(us h) { return __uint_as_float(((unsigned)h) << 16); }

__device__ inline void store_split(us* __restrict__ hi, us* __restrict__ lo, size_t idx, float v) {
  us h = f2bf(v);
  hi[idx] = h;
  lo[idx] = f2bf(v - bf2f(h));
}

// ---------------- elementwise split / convert ----------------
__global__ void ga_split(const float* __restrict__ src, us* __restrict__ hi,
                         us* __restrict__ lo, long n) {
  long i0 = ((long)blockIdx.x * blockDim.x + threadIdx.x) * 4;
  long stride = (long)gridDim.x * blockDim.x * 4;
  for (long i = i0; i < n; i += stride) {
    float4 v = *reinterpret_cast<const float4*>(src + i);
    ushort4 h, l;
    h.x = f2bf(v.x); l.x = f2bf(v.x - bf2f(h.x));
    h.y = f2bf(v.y); l.y = f2bf(v.y - bf2f(h.y));
    h.z = f2bf(v.z); l.z = f2bf(v.z - bf2f(h.z));
    h.w = f2bf(v.w); l.w = f2bf(v.w - bf2f(h.w));
    *reinterpret_cast<ushort4*>(hi + i) = h;
    *reinterpret_cast<ushort4*>(lo + i) = l;
  }
}

__global__ void ga_cvt(const float* __restrict__ src, us* __restrict__ dst, long n) {
  long i0 = ((long)blockIdx.x * blockDim.x + threadIdx.x) * 4;
  long stride = (long)gridDim.x * blockDim.x * 4;
  for (long i = i0; i < n; i += stride) {
    float4 v = *reinterpret_cast<const float4*>(src + i);
    ushort4 h;
    h.x = f2bf(v.x); h.y = f2bf(v.y); h.z = f2bf(v.z); h.w = f2bf(v.w);
    *reinterpret_cast<ushort4*>(dst + i) = h;
  }
}

// ---------------- ctx transpose+split: [B][S][D] f32 -> [B][D][S] bf16 hi/lo ----------------
__global__ void ga_transpose_split(const float* __restrict__ ctx, us* __restrict__ tHi,
                                   us* __restrict__ tLo) {
  __shared__ float tile[64][65];
  int s0 = blockIdx.x << 6, d0 = blockIdx.y << 6, b = blockIdx.z;
  const float* src = ctx + (size_t)b * NS * ND;
  int tid = threadIdx.x;
#pragma unroll
  for (int i = 0; i < 16; ++i) {
    int lin = (i << 8) + tid;
    int r = lin >> 6, c = lin & 63;
    tile[r][c] = src[(size_t)(s0 + r) * ND + d0 + c];
  }
  __syncthreads();
  us* oH = tHi + (size_t)b * ND * NS;
  us* oL = tLo + (size_t)b * ND * NS;
#pragma unroll
  for (int i = 0; i < 16; ++i) {
    int lin = (i << 8) + tid;
    int dr = lin >> 6, sc = lin & 63;
    float v = tile[sc][dr];
    size_t o = (size_t)(d0 + dr) * NS + s0 + sc;
    us h = f2bf(v);
    oH[o] = h;
    oL[o] = f2bf(v - bf2f(h));
  }
}

// ---------------- row softmax, in-place f32 + split planes ----------------
__global__ __launch_bounds__(256) void ga_softmax(float* __restrict__ al,
                                                  us* __restrict__ pHi, us* __restrict__ pLo) {
  int row = blockIdx.x;  // t*32 + b
  int tid = threadIdx.x;
  float* p = al + (size_t)row * NS;
  float4 v = *reinterpret_cast<const float4*>(p + (tid << 2));
  float m = fmaxf(fmaxf(v.x, v.y), fmaxf(v.z, v.w));
#pragma unroll
  for (int off = 32; off; off >>= 1) m = fmaxf(m, __shfl_xor(m, off));
  __shared__ float rmax[4], rsum[4];
  int wv = tid >> 6, ln = tid & 63;
  if (ln == 0) rmax[wv] = m;
  __syncthreads();
  m = fmaxf(fmaxf(rmax[0], rmax[1]), fmaxf(rmax[2], rmax[3]));
  float4 e;
  e.x = __expf(v.x - m); e.y = __expf(v.y - m);
  e.z = __expf(v.z - m); e.w = __expf(v.w - m);
  float s = e.x + e.y + e.z + e.w;
#pragma unroll
  for (int off = 32; off; off >>= 1) s += __shfl_xor(s, off);
  if (ln == 0) rsum[wv] = s;
  __syncthreads();
  s = rsum[0] + rsum[1] + rsum[2] + rsum[3];
  float inv = 1.0f / s;
  e.x *= inv; e.y *= inv; e.z *= inv; e.w *= inv;
  *reinterpret_cast<float4*>(p + (tid << 2)) = e;
  int t = row >> 5, b = row & 31;
  size_t o = ((size_t)b * NT_ + t) * NS + (tid << 2);
  ushort4 h, l;
  h.x = f2bf(e.x); l.x = f2bf(e.x - bf2f(h.x));
  h.y = f2bf(e.y); l.y = f2bf(e.y - bf2f(h.y));
  h.z = f2bf(e.z); l.z = f2bf(e.z - bf2f(h.z));
  h.w = f2bf(e.w); l.w = f2bf(e.w - bf2f(h.w));
  *reinterpret_cast<ushort4*>(pHi + o) = h;
  *reinterpret_cast<ushort4*>(pLo + o) = l;
}

// ---------------- chunked split-bf16 GEMM engine (128x128, 4 waves) ----------------
__device__ inline void gload16(const us* g, void* l) {
  __builtin_amdgcn_global_load_lds((const __attribute__((address_space(1))) unsigned int*)g,
                                   (__attribute__((address_space(3))) unsigned int*)l, 16, 0, 0);
}

__device__ inline f32x4 mfma16(bf16x8 a, bf16x8 b, f32x4 c) {
  return __builtin_amdgcn_mfma_f32_16x16x32_bf16(a, b, c, 0, 0, 0);
}

#define VM0 asm volatile("s_waitcnt vmcnt(0)" ::: "memory")
#define VM2 asm volatile("s_waitcnt vmcnt(2)" ::: "memory")
#define VM4 asm volatile("s_waitcnt vmcnt(4)" ::: "memory")

// planes (bytes, within buffer): Ah 0, Al 8192, Bh 16384, Bl 24576(3-term)
#define STG_AH(C) do {                                                             \
    const us* b_; long col_;                                                       \
    if constexpr (MODE == 3) {                                                     \
      if ((C) < 32) { b_ = pA0; col_ = (long)(C) << 5; }                           \
      else          { b_ = pA2; col_ = (long)((C) - 32) << 5; }                    \
    } else { b_ = pA0; col_ = (long)(C) << 5; }                                    \
    const us* g_ = b_ + col_ + aOff;                                               \
    char* d_ = lb + (((C) & 1) ? BUFSZ : 0) + (tid << 4);                          \
    gload16(g_, d_); gload16(g_ + 65536, d_ + 4096);                               \
  } while (0)

#define STG_AL(C) do {                                                             \
    const us* b_; long col_;                                                       \
    if constexpr (MODE == 3) {                                                     \
      if ((C) < 32) { b_ = pA1; col_ = (long)(C) << 5; }                           \
      else          { b_ = pA3; col_ = (long)((C) - 32) << 5; }                    \
    } else { b_ = pA1; col_ = (long)(C) << 5; }                                    \
    const us* g_ = b_ + col_ + aOff;                                               \
    char* d_ = lb + (((C) & 1) ? BUFSZ : 0) + 8192 + (tid << 4);                   \
    gload16(g_, d_); gload16(g_ + 65536, d_ + 4096);                               \
  } while (0)

#define STG_BH(C) do {                                                             \
    const us* g_ = pB0 + ((long)(C) << 5) + bOff;                                  \
    char* d_ = lb + (((C) & 1) ? BUFSZ : 0) + 16384 + (tid << 4);                  \
    gload16(g_, d_); gload16(g_ + ((long)LDB << 6), d_ + 4096);                    \
  } while (0)

#define STG_BL(C) do {                                                             \
    const us* g_ = pB1 + ((long)(C) << 5) + bOff;                                  \
    char* d_ = lb + (((C) & 1) ? BUFSZ : 0) + 24576 + (tid << 4);                  \
    gload16(g_, d_); gload16(g_ + ((long)LDB << 6), d_ + 4096);                    \
  } while (0)

#define RD4(BP, PO, BASE, ARR) do {                                                \
    const char* p_ = (BP) + (PO) + (BASE);                                         \
    _Pragma("unroll") for (int q_ = 0; q_ < 4; ++q_)                               \
      ARR[q_] = *(const bf16x8*)(p_ + (q_ << 10) + colx);                          \
  } while (0)

#define MM16(AA, BB)                                                               \
  _Pragma("unroll") for (int m_ = 0; m_ < 4; ++m_)                                 \
  _Pragma("unroll") for (int n_ = 0; n_ < 4; ++n_)                                 \
    acc[m_][n_] = mfma16(AA[m_], BB[n_], acc[m_][n_])

#define PH(RDS, MMQ, POST) do {                                                    \
    __builtin_amdgcn_s_barrier();                                                  \
    RDS;                                                                           \
    __builtin_amdgcn_s_setprio(1);                                                 \
    MMQ;                                                                           \
    __builtin_amdgcn_s_setprio(0);                                                 \
    POST;                                                                          \
  } while (0)

// MODE 0: GEMM1 h=in*W_in^T -> h planes.          grid(128,8)
// MODE 1: GEMM2 align=h*ctx^T -> f32 align.       grid(1024) XCD-swz
// MODE 2: GEMM3 c=P*ctxT^T -> c planes.           grid(1024) XCD-swz
// MODE 3: GEMM4 tanh(concat*W_out^T) -> out.      grid(128,8), 2-term
template <int MODE>
__global__ __launch_bounds__(256, 2) void ga_ge(
    const us* __restrict__ Ahi, const us* __restrict__ Alo,
    const us* __restrict__ A2hi, const us* __restrict__ A2lo,
    const us* __restrict__ Bhi, const us* __restrict__ Blo,
    void* __restrict__ out0, void* __restrict__ out1,
    long astride, long bstride) {
  constexpr int LDB = (MODE == 3) ? 2048 : 1024;
  constexpr int NC = (MODE == 3) ? 64 : 32;
  constexpr int BUFSZ = (MODE == 3) ? 24576 : 32768;
  __shared__ __align__(16) char lds[2 * BUFSZ];
  char* lb = lds;
  const int tid = threadIdx.x;
  const int lane = tid & 63;
  const int fr = lane & 15;
  const int wv = tid >> 6;
  const int wr = wv >> 1, wc = wv & 1;  // 2M x 2N waves, per-wave 64x64

  // block decode
  int rowA, colB, bz;
  if constexpr (MODE == 1 || MODE == 2) {
    const int bi = blockIdx.x;            // 0..1023, XCD ~= bi & 7
    const int j = bi >> 3;                // 0..127 within XCD
    bz = ((bi & 7) << 2) + (j & 3);       // 4 batches per XCD
    const int panel = j >> 2;             // 0..31 = 4 rowA x 8 colB
    rowA = (panel & 3) << 7;
    colB = (panel >> 2) << 7;
  } else {
    rowA = blockIdx.x << 7;
    colB = blockIdx.y << 7;
    bz = blockIdx.z;
  }

  // plane base pointers (uniform -> SGPR)
  const us* pA0 = Ahi + (size_t)bz * astride + (size_t)rowA * 1024;
  const us* pA1 = Alo + (size_t)bz * astride + (size_t)rowA * 1024;
  const us* pA2 = (MODE == 3) ? A2hi + (size_t)rowA * 1024 : nullptr;
  const us* pA3 = (MODE == 3) ? A2lo + (size_t)rowA * 1024 : nullptr;
  const us* pB0 = Bhi + (size_t)bz * bstride + (size_t)colB * LDB;
  const us* pB1 = (MODE == 3) ? nullptr : Blo + (size_t)bz * bstride + (size_t)colB * LDB;

  // staging: thread covers plane rows tid>>2 and +64; pre-swizzled source col
  const int swc = ((tid & 3) ^ ((tid >> 3) & 3)) << 3;
  const long aOff = (long)(tid >> 2) * 1024 + swc;
  const long bOff = (long)(tid >> 2) * LDB + swc;

  // frag-read geometry: plane row = (w*64) + q*16 + fr; swizzled granule.
  // NOTE r13 fix: bRd holds only the within-plane offset; the plane base
  // (16384/24576) is passed as PO by the caller (r12 double-added -> OOB).
  const int colx = (((lane >> 4) ^ ((fr >> 1) & 3)) << 4);
  const int aRd = (wr << 12) + (fr << 6);
  const int bRd = (wc << 12) + (fr << 6);

  bf16x8 ah[4], al[4], bh[4], bl[4];
  f32x4 zero = {0.f, 0.f, 0.f, 0.f};
  f32x4 acc[4][4];
#pragma unroll
  for (int i = 0; i < 4; ++i)
#pragma unroll
    for (int k = 0; k < 4; ++k) acc[i][k] = zero;

  // prologue: chunk0 all planes + chunk1 {Ah,Bh}
  if constexpr (MODE != 3) {
    STG_AH(0); STG_BH(0); STG_BL(0); STG_AL(0);
    STG_AH(1); STG_BH(1);
  } else {
    STG_AH(0); STG_BH(0); STG_AL(0);
    STG_AH(1); STG_BH(1);
  }
  VM0;
  __builtin_amdgcn_s_barrier();

  if constexpr (MODE != 3) {
    for (int c = 0; c < NC - 2; ++c) {
      const char* bp = lb + ((c & 1) ? BUFSZ : 0);
      PH({ RD4(bp, 16384, bRd, bh); RD4(bp, 0, aRd, ah); }, MM16(ah, bh),
         { STG_AL(c + 1); STG_BL(c + 1); VM4; });
      PH({ RD4(bp, 24576, bRd, bl); RD4(bp, 8192, aRd, al); },
         { MM16(ah, bl); MM16(al, bh); },
         { STG_AH(c + 2); STG_BH(c + 2); VM4; });
    }
    {  // c = NC-2: ph1 stages last Al/Bl then drains everything
      const char* bp = lb + (((NC - 2) & 1) ? BUFSZ : 0);
      PH({ RD4(bp, 16384, bRd, bh); RD4(bp, 0, aRd, ah); }, MM16(ah, bh),
         { STG_AL(NC - 1); STG_BL(NC - 1); VM0; });
      PH({ RD4(bp, 24576, bRd, bl); RD4(bp, 8192, aRd, al); },
         { MM16(ah, bl); MM16(al, bh); }, {});
    }
    {  // c = NC-1
      const char* bp = lb + (((NC - 1) & 1) ? BUFSZ : 0);
      PH({ RD4(bp, 16384, bRd, bh); RD4(bp, 0, aRd, ah); }, MM16(ah, bh), {});
      PH({ RD4(bp, 24576, bRd, bl); RD4(bp, 8192, aRd, al); },
         { MM16(ah, bl); MM16(al, bh); }, {});
    }
  } else {
    for (int c = 0; c < NC - 2; ++c) {
      const char* bp = lb + ((c & 1) ? BUFSZ : 0);
      PH({ RD4(bp, 16384, bRd, bh); RD4(bp, 0, aRd, ah); }, MM16(ah, bh),
         { STG_AL(c + 1); VM2; });
      PH({ RD4(bp, 8192, aRd, al); }, MM16(al, bh),
         { STG_AH(c + 2); STG_BH(c + 2); VM4; });
    }
    {  // c = NC-2
      const char* bp = lb + (((NC - 2) & 1) ? BUFSZ : 0);
      PH({ RD4(bp, 16384, bRd, bh); RD4(bp, 0, aRd, ah); }, MM16(ah, bh),
         { STG_AL(NC - 1); VM0; });
      PH({ RD4(bp, 8192, aRd, al); }, MM16(al, bh), {});
    }
    {  // c = NC-1
      const char* bp = lb + (((NC - 1) & 1) ? BUFSZ : 0);
      PH({ RD4(bp, 16384, bRd, bh); RD4(bp, 0, aRd, ah); }, MM16(ah, bh), {});
      PH({ RD4(bp, 8192, aRd, al); }, MM16(al, bh), {});
    }
  }

  // epilogue: C/D layout col=lane&15, row=(lane>>4)*4+j
#pragma unroll
  for (int mf = 0; mf < 4; ++mf)
#pragma unroll
    for (int nf = 0; nf < 4; ++nf)
#pragma unroll
      for (int j = 0; j < 4; ++j) {
        int r = rowA + (wr << 6) + (mf << 4) + (((lane >> 4) & 3) << 2) + j;
        int c = colB + (wc << 6) + (nf << 4) + fr;
        float v = acc[mf][nf][j];
        if constexpr (MODE == 0) {
          store_split((us*)out0, (us*)out1, (size_t)r * 1024 + c, v);
        } else if constexpr (MODE == 1) {
          ((float*)out0)[((size_t)r * NB + bz) * NS + c] = v;  // align[t][b][s]
        } else if constexpr (MODE == 2) {
          store_split((us*)out0, (us*)out1, ((size_t)bz * 512 + r) * 1024 + c, v);
        } else {
          int bb = r >> 9, tt2 = r & 511;
          ((float*)out0)[((size_t)tt2 * NB + bb) * ND + c] = tanhf(v);  // attn[t][b][d]
        }
      }
}

// ---------------- launch ----------------
extern "C" void kernel_launch(void* const* d_in, const int* in_sizes, int n_in,
                              void* d_out, int out_size, void* d_ws, size_t ws_size,
                              hipStream_t stream) {
  (void)in_sizes; (void)n_in; (void)out_size; (void)ws_size;
  const float* inp = (const float*)d_in[0];   // [32][512][1024]
  const float* ctx = (const float*)d_in[1];   // [32][1024][1024]
  const float* Win = (const float*)d_in[2];   // [1024][1024] (e,d)
  const float* Wout = (const float*)d_in[3];  // [1024][2048] (d,f)
  float* out = (float*)d_out;

  char* w = (char*)d_ws;
  us* ctx_hi  = (us*)(w + 0);
  us* c_hi    = (us*)(w + 0);
  us* c_lo    = (us*)(w + 33554432);
  us* ctx_lo  = (us*)(w + 67108864);
  us* p_hi    = (us*)(w + 67108864);
  us* p_lo    = (us*)(w + 100663296);
  us* in_hi   = (us*)(w + 134217728);
  us* in_lo   = (us*)(w + 167772160);
  us* h_hi    = (us*)(w + 201326592);
  us* h_lo    = (us*)(w + 234881024);
  us* ctxT_lo = (us*)(w + 201326592);  // reuses h region after GEMM2
  us* win_hi  = (us*)(w + 268435456);
  us* win_lo  = (us*)(w + 270532608);
  us* wout_b  = (us*)(w + 272629760);

  us* ctxT_hi = (us*)d_out;            // attn region as scratch until GEMM4
  float* alignOut = out + 16777216;    // second half of d_out

  ga_split<<<2048, 256, 0, stream>>>(inp, in_hi, in_lo, 16777216L);
  ga_split<<<2048, 256, 0, stream>>>(ctx, ctx_hi, ctx_lo, 33554432L);
  ga_split<<<512, 256, 0, stream>>>(Win, win_hi, win_lo, 1048576L);
  ga_cvt<<<512, 256, 0, stream>>>(Wout, wout_b, 2097152L);

  // GEMM1: h = in @ W_in^T   (M=16384, N=1024, 3-term chunks)
  ga_ge<0><<<dim3(128, 8, 1), 256, 0, stream>>>(in_hi, in_lo, nullptr, nullptr,
                                                win_hi, win_lo, h_hi, h_lo, 0L, 0L);
  // GEMM2: align = h @ ctx^T (batched 32; M=512, N=1024) [XCD swz]
  ga_ge<1><<<dim3(1024, 1, 1), 256, 0, stream>>>(h_hi, h_lo, nullptr, nullptr,
                                                 ctx_hi, ctx_lo, alignOut, nullptr,
                                                 524288L, 1048576L);
  // ctx transpose+split (overwrites h region -> must follow GEMM2; stream-ordered)
  ga_transpose_split<<<dim3(16, 16, 32), 256, 0, stream>>>(ctx, ctxT_hi, ctxT_lo);
  // softmax in-place + P split planes
  ga_softmax<<<16384, 256, 0, stream>>>(alignOut, p_hi, p_lo);
  // GEMM3: c = P @ ctx (via ctxT planes; batched) [XCD swz]
  ga_ge<2><<<dim3(1024, 1, 1), 256, 0, stream>>>(p_hi, p_lo, nullptr, nullptr,
                                                 ctxT_hi, ctxT_lo, c_hi, c_lo,
                                                 524288L, 1048576L);
  // GEMM4: attn = tanh(concat[c,in] @ W_out^T) (2-term, 64 chunks)
  ga_ge<3><<<dim3(128, 8, 1), 256, 0, stream>>>(c_hi, c_lo, in_hi, in_lo,
                                                wout_b, nullptr, out, nullptr, 0L, 0L);
}

// Round 14
// 591.218 us; speedup vs baseline: 1.1593x; 1.1593x over previous
//
#include <hip/hip_runtime.h>
#include <hip/hip_bf16.h>

// GlobalAttention (general): B=32, T=512, S=1024, D=1024, f32 in/out.
// Round-14 = round-11 chunk engine (best: 554us) with v_mfma_f32_32x32x16
// replacing 16x16x32: same FLOPs in HALF the MFMA instructions (issue-slot
// pressure test; 32x32 pipe also ~15% faster per ubench). Frag/epilogue
// 32x32 mappings are r4-verified (passed absmax 0.0098).
// Engine: 256x256 tile, 8 waves (2Mx4N, per-wave 128x64 = 4x2 frags of
// 32x32), chunk planes {Ah,Al,Bh[,Bl]} of 256r x 32c staged once/chunk;
// 3 phases (3-term): MM(Ah,Bh) / MM(Ah,Bl) [Ah in regs] / MM(Al,Bh)
// [Bh in regs]; 2-term: MM(Ah,B) / MM(Al,B). 16 MFMA(32x32)/phase/wave.
// Stage ledger (r11, audited): ph1 stages Al(c+1); ph2 stages Ah,Bh(c+2);
// ph3 stages Bl(c+2); tails VM8 (VM6 2-term); peel (NC-2).ph1 -> VM0.
// Swizzle: phys 16B-granule g = logical ^ ((row>>1)&3), both-sides.
// XCD decode (batched modes): 256 blocks, each XCD owns 4 batches.

typedef short bf16x8 __attribute__((ext_vector_type(8)));
typedef float f32x16 __attribute__((ext_vector_type(16)));
typedef unsigned short us;

#define NB 32
#define NT_ 512
#define NS 1024
#define ND 1024

__device__ inline us f2bf(float x) {
  unsigned u = __float_as_uint(x);
  u += 0x7FFFu + ((u >> 16) & 1u);
  return (us)(u >> 16);
}
__device__ inline float bf2f(us h) { return __uint_as_float(((unsigned)h) << 16); }

__device__ inline void store_split(us* __restrict__ hi, us* __restrict__ lo, size_t idx, float v) {
  us h = f2bf(v);
  hi[idx] = h;
  lo[idx] = f2bf(v - bf2f(h));
}

// ---------------- elementwise split / convert ----------------
__global__ void ga_split(const float* __restrict__ src, us* __restrict__ hi,
                         us* __restrict__ lo, long n) {
  long i0 = ((long)blockIdx.x * blockDim.x + threadIdx.x) * 4;
  long stride = (long)gridDim.x * blockDim.x * 4;
  for (long i = i0; i < n; i += stride) {
    float4 v = *reinterpret_cast<const float4*>(src + i);
    ushort4 h, l;
    h.x = f2bf(v.x); l.x = f2bf(v.x - bf2f(h.x));
    h.y = f2bf(v.y); l.y = f2bf(v.y - bf2f(h.y));
    h.z = f2bf(v.z); l.z = f2bf(v.z - bf2f(h.z));
    h.w = f2bf(v.w); l.w = f2bf(v.w - bf2f(h.w));
    *reinterpret_cast<ushort4*>(hi + i) = h;
    *reinterpret_cast<ushort4*>(lo + i) = l;
  }
}

__global__ void ga_cvt(const float* __restrict__ src, us* __restrict__ dst, long n) {
  long i0 = ((long)blockIdx.x * blockDim.x + threadIdx.x) * 4;
  long stride = (long)gridDim.x * blockDim.x * 4;
  for (long i = i0; i < n; i += stride) {
    float4 v = *reinterpret_cast<const float4*>(src + i);
    ushort4 h;
    h.x = f2bf(v.x); h.y = f2bf(v.y); h.z = f2bf(v.z); h.w = f2bf(v.w);
    *reinterpret_cast<ushort4*>(dst + i) = h;
  }
}

// ---------------- ctx transpose+split: [B][S][D] f32 -> [B][D][S] bf16 hi/lo ----------------
__global__ void ga_transpose_split(const float* __restrict__ ctx, us* __restrict__ tHi,
                                   us* __restrict__ tLo) {
  __shared__ float tile[64][65];
  int s0 = blockIdx.x << 6, d0 = blockIdx.y << 6, b = blockIdx.z;
  const float* src = ctx + (size_t)b * NS * ND;
  int tid = threadIdx.x;
#pragma unroll
  for (int i = 0; i < 16; ++i) {
    int lin = (i << 8) + tid;
    int r = lin >> 6, c = lin & 63;
    tile[r][c] = src[(size_t)(s0 + r) * ND + d0 + c];
  }
  __syncthreads();
  us* oH = tHi + (size_t)b * ND * NS;
  us* oL = tLo + (size_t)b * ND * NS;
#pragma unroll
  for (int i = 0; i < 16; ++i) {
    int lin = (i << 8) + tid;
    int dr = lin >> 6, sc = lin & 63;
    float v = tile[sc][dr];
    size_t o = (size_t)(d0 + dr) * NS + s0 + sc;
    us h = f2bf(v);
    oH[o] = h;
    oL[o] = f2bf(v - bf2f(h));
  }
}

// ---------------- row softmax, in-place f32 + split planes ----------------
__global__ __launch_bounds__(256) void ga_softmax(float* __restrict__ al,
                                                  us* __restrict__ pHi, us* __restrict__ pLo) {
  int row = blockIdx.x;  // t*32 + b
  int tid = threadIdx.x;
  float* p = al + (size_t)row * NS;
  float4 v = *reinterpret_cast<const float4*>(p + (tid << 2));
  float m = fmaxf(fmaxf(v.x, v.y), fmaxf(v.z, v.w));
#pragma unroll
  for (int off = 32; off; off >>= 1) m = fmaxf(m, __shfl_xor(m, off));
  __shared__ float rmax[4], rsum[4];
  int wv = tid >> 6, ln = tid & 63;
  if (ln == 0) rmax[wv] = m;
  __syncthreads();
  m = fmaxf(fmaxf(rmax[0], rmax[1]), fmaxf(rmax[2], rmax[3]));
  float4 e;
  e.x = __expf(v.x - m); e.y = __expf(v.y - m);
  e.z = __expf(v.z - m); e.w = __expf(v.w - m);
  float s = e.x + e.y + e.z + e.w;
#pragma unroll
  for (int off = 32; off; off >>= 1) s += __shfl_xor(s, off);
  if (ln == 0) rsum[wv] = s;
  __syncthreads();
  s = rsum[0] + rsum[1] + rsum[2] + rsum[3];
  float inv = 1.0f / s;
  e.x *= inv; e.y *= inv; e.z *= inv; e.w *= inv;
  *reinterpret_cast<float4*>(p + (tid << 2)) = e;
  int t = row >> 5, b = row & 31;
  size_t o = ((size_t)b * NT_ + t) * NS + (tid << 2);
  ushort4 h, l;
  h.x = f2bf(e.x); l.x = f2bf(e.x - bf2f(h.x));
  h.y = f2bf(e.y); l.y = f2bf(e.y - bf2f(h.y));
  h.z = f2bf(e.z); l.z = f2bf(e.z - bf2f(h.z));
  h.w = f2bf(e.w); l.w = f2bf(e.w - bf2f(h.w));
  *reinterpret_cast<ushort4*>(pHi + o) = h;
  *reinterpret_cast<ushort4*>(pLo + o) = l;
}

// ---------------- chunked split-bf16 GEMM engine (32x32 MFMA) ----------------
__device__ inline void gload16(const us* g, void* l) {
  __builtin_amdgcn_global_load_lds((const __attribute__((address_space(1))) unsigned int*)g,
                                   (__attribute__((address_space(3))) unsigned int*)l, 16, 0, 0);
}

__device__ inline f32x16 mfma32(bf16x8 a, bf16x8 b, f32x16 c) {
  return __builtin_amdgcn_mfma_f32_32x32x16_bf16(a, b, c, 0, 0, 0);
}

#define VM0 asm volatile("s_waitcnt vmcnt(0)" ::: "memory")
#define VMS do { if constexpr (MODE != 3)                                          \
                   asm volatile("s_waitcnt vmcnt(8)" ::: "memory");                \
                 else asm volatile("s_waitcnt vmcnt(6)" ::: "memory"); } while (0)

#define STG_AH(C) do {                                                             \
    const us* b_; long col_;                                                       \
    if constexpr (MODE == 3) {                                                     \
      if ((C) < 32) { b_ = pA0; col_ = (long)(C) << 5; }                           \
      else          { b_ = pA2; col_ = (long)((C) - 32) << 5; }                    \
    } else { b_ = pA0; col_ = (long)(C) << 5; }                                    \
    const us* g_ = b_ + col_ + aOff;                                               \
    char* d_ = lb + (((C) & 1) ? BUFSZ : 0) + (tid << 4);                          \
    gload16(g_, d_); gload16(g_ + 131072, d_ + 8192);                              \
  } while (0)

#define STG_AL(C) do {                                                             \
    const us* b_; long col_;                                                       \
    if constexpr (MODE == 3) {                                                     \
      if ((C) < 32) { b_ = pA1; col_ = (long)(C) << 5; }                           \
      else          { b_ = pA3; col_ = (long)((C) - 32) << 5; }                    \
    } else { b_ = pA1; col_ = (long)(C) << 5; }                                    \
    const us* g_ = b_ + col_ + aOff;                                               \
    char* d_ = lb + (((C) & 1) ? BUFSZ : 0) + 16384 + (tid << 4);                  \
    gload16(g_, d_); gload16(g_ + 131072, d_ + 8192);                              \
  } while (0)

#define STG_BH(C) do {                                                             \
    const us* g_ = pB0 + ((long)(C) << 5) + bOff;                                  \
    char* d_ = lb + (((C) & 1) ? BUFSZ : 0) + 32768 + (tid << 4);                  \
    gload16(g_, d_); gload16(g_ + ((long)LDB << 7), d_ + 8192);                    \
  } while (0)

#define STG_BL(C) do {                                                             \
    const us* g_ = pB1 + ((long)(C) << 5) + bOff;                                  \
    char* d_ = lb + (((C) & 1) ? BUFSZ : 0) + 49152 + (tid << 4);                  \
    gload16(g_, d_); gload16(g_ + ((long)LDB << 7), d_ + 8192);                    \
  } while (0)

// 32x32 frag reads: lane row = base + (lane&31); kstep ks granule
// logical g = 2*ks + (lane>>5), phys = g ^ ((l31>>1)&3)  [r4-verified]
#define RD_A32(BP, PO) do {                                                        \
    const char* p_ = (BP) + (PO) + aRd;                                            \
    _Pragma("unroll") for (int m_ = 0; m_ < 4; ++m_) {                             \
      a8[m_][0] = *(const bf16x8*)(p_ + (m_ << 11) + colx0);                       \
      a8[m_][1] = *(const bf16x8*)(p_ + (m_ << 11) + colx1);                       \
    }                                                                              \
  } while (0)

#define RD_B32(BP, PO, ARR) do {                                                   \
    const char* p_ = (BP) + (PO) + bRd;                                            \
    _Pragma("unroll") for (int n_ = 0; n_ < 2; ++n_) {                             \
      ARR[n_][0] = *(const bf16x8*)(p_ + (n_ << 11) + colx0);                      \
      ARR[n_][1] = *(const bf16x8*)(p_ + (n_ << 11) + colx1);                      \
    }                                                                              \
  } while (0)

#define MM16T(BB)                                                                  \
  _Pragma("unroll") for (int ks_ = 0; ks_ < 2; ++ks_)                              \
  _Pragma("unroll") for (int m_ = 0; m_ < 4; ++m_)                                 \
  _Pragma("unroll") for (int n_ = 0; n_ < 2; ++n_)                                 \
    acc[m_][n_] = mfma32(a8[m_][ks_], BB[n_][ks_], acc[m_][n_])

#define PH(RDS, MMQ, POST) do {                                                    \
    __builtin_amdgcn_s_barrier();                                                  \
    RDS;                                                                           \
    __builtin_amdgcn_s_setprio(1);                                                 \
    MMQ;                                                                           \
    __builtin_amdgcn_s_setprio(0);                                                 \
    POST;                                                                          \
  } while (0)

// MODE 0: GEMM1 h=in*W_in^T -> h planes.          grid(64,4,1)
// MODE 1: GEMM2 align=h*ctx^T -> f32 align.       grid(256) XCD-swz
// MODE 2: GEMM3 c=P*ctxT^T -> c planes.           grid(256) XCD-swz
// MODE 3: GEMM4 tanh(concat*W_out^T) -> out.      grid(64,4,1), 2-term
template <int MODE>
__global__ __launch_bounds__(512, 1) void ga_gf(
    const us* __restrict__ Ahi, const us* __restrict__ Alo,
    const us* __restrict__ A2hi, const us* __restrict__ A2lo,
    const us* __restrict__ Bhi, const us* __restrict__ Blo,
    void* __restrict__ out0, void* __restrict__ out1,
    long astride, long bstride) {
  constexpr int LDB = (MODE == 3) ? 2048 : 1024;
  constexpr int NC = (MODE == 3) ? 64 : 32;
  constexpr int BUFSZ = (MODE == 3) ? 49152 : 65536;
  __shared__ __align__(16) char lds[2 * BUFSZ];
  char* lb = lds;
  const int tid = threadIdx.x;
  const int lane = tid & 63;
  const int l31 = lane & 31;
  const int hi5 = lane >> 5;
  const int wv = tid >> 6;
  const int wr = wv >> 2, wc = wv & 3;  // 2M x 4N waves, per-wave 128x64

  // block decode: XCD-aware for batched modes (each XCD owns 4 batches)
  int rowA, colB, bz;
  if constexpr (MODE == 1 || MODE == 2) {
    const int bi = blockIdx.x;            // 0..255, XCD ~= bi & 7
    const int j = bi >> 3;                // 0..31 within XCD
    bz = ((bi & 7) << 2) + (j & 3);       // 4 batches per XCD
    const int panel = j >> 2;             // 0..7 = 2 rowA x 4 colB
    rowA = (panel & 1) << 8;
    colB = (panel >> 1) << 8;
  } else {
    rowA = blockIdx.x << 8;
    colB = blockIdx.y << 8;
    bz = blockIdx.z;
  }

  // plane base pointers (uniform -> SGPR)
  const us* pA0 = Ahi + (size_t)bz * astride + (size_t)rowA * 1024;
  const us* pA1 = Alo + (size_t)bz * astride + (size_t)rowA * 1024;
  const us* pA2 = (MODE == 3) ? A2hi + (size_t)rowA * 1024 : nullptr;
  const us* pA3 = (MODE == 3) ? A2lo + (size_t)rowA * 1024 : nullptr;
  const us* pB0 = Bhi + (size_t)bz * bstride + (size_t)colB * LDB;
  const us* pB1 = (MODE == 3) ? nullptr : Blo + (size_t)bz * bstride + (size_t)colB * LDB;

  // staging geometry: thread covers rows tid>>2 and +128 of a 256x32 plane;
  // pre-swizzled source col (elements); linear LDS dest tid*16 (+8192).
  const int swc = ((tid & 3) ^ ((tid >> 3) & 3)) << 3;
  const long aOff = (long)(tid >> 2) * 1024 + swc;
  const long bOff = (long)(tid >> 2) * LDB + swc;

  // frag-read geometry (32x32, r4-verified): row = base + l31; granule
  // for kstep ks: phys = (2*ks + hi5) ^ ((l31>>1)&3)
  const int s_ = (l31 >> 1) & 3;
  const int colx0 = ((hi5 ^ s_) << 4);
  const int colx1 = (((2 | hi5) ^ s_) << 4);
  const int aRd = (wr << 13) + (l31 << 6);
  const int bRd = (wc << 12) + (l31 << 6);

  bf16x8 a8[4][2], bh[2][2], bl2[2][2];
  f32x16 acc[4][2];
#pragma unroll
  for (int m = 0; m < 4; ++m)
#pragma unroll
    for (int n = 0; n < 2; ++n)
#pragma unroll
      for (int g = 0; g < 16; ++g) acc[m][n][g] = 0.f;

  // prologue: chunk0 all planes + chunk1 {Ah,Bh[,Bl]} (Al(1) staged c0.ph1)
  if constexpr (MODE != 3) {
    STG_AH(0); STG_BH(0); STG_BL(0); STG_AL(0);
    STG_AH(1); STG_BH(1); STG_BL(1);
  } else {
    STG_AH(0); STG_BH(0); STG_AL(0);
    STG_AH(1); STG_BH(1);
  }
  VM0;
  __builtin_amdgcn_s_barrier();

  if constexpr (MODE != 3) {
    for (int c = 0; c < NC - 2; ++c) {
      const char* bp = lb + ((c & 1) ? BUFSZ : 0);
      PH({ RD_B32(bp, 32768, bh); RD_A32(bp, 0); }, MM16T(bh),
         { STG_AL(c + 1); VMS; });
      PH({ RD_B32(bp, 49152, bl2); }, MM16T(bl2),
         { STG_AH(c + 2); STG_BH(c + 2); VMS; });
      PH({ RD_A32(bp, 16384); }, MM16T(bh),
         { STG_BL(c + 2); VMS; });
    }
    {  // c = NC-2: stage only Al(NC-1); VM0 publishes everything
      const char* bp = lb + (((NC - 2) & 1) ? BUFSZ : 0);
      PH({ RD_B32(bp, 32768, bh); RD_A32(bp, 0); }, MM16T(bh),
         { STG_AL(NC - 1); VM0; });
      PH({ RD_B32(bp, 49152, bl2); }, MM16T(bl2), {});
      PH({ RD_A32(bp, 16384); }, MM16T(bh), {});
    }
    {  // c = NC-1
      const char* bp = lb + (((NC - 1) & 1) ? BUFSZ : 0);
      PH({ RD_B32(bp, 32768, bh); RD_A32(bp, 0); }, MM16T(bh), {});
      PH({ RD_B32(bp, 49152, bl2); }, MM16T(bl2), {});
      PH({ RD_A32(bp, 16384); }, MM16T(bh), {});
    }
  } else {
    for (int c = 0; c < NC - 2; ++c) {
      const char* bp = lb + ((c & 1) ? BUFSZ : 0);
      PH({ RD_B32(bp, 32768, bh); RD_A32(bp, 0); }, MM16T(bh),
         { STG_AL(c + 1); VMS; });
      PH({ RD_A32(bp, 16384); }, MM16T(bh),
         { STG_AH(c + 2); STG_BH(c + 2); VMS; });
    }
    {  // c = NC-2
      const char* bp = lb + (((NC - 2) & 1) ? BUFSZ : 0);
      PH({ RD_B32(bp, 32768, bh); RD_A32(bp, 0); }, MM16T(bh),
         { STG_AL(NC - 1); VM0; });
      PH({ RD_A32(bp, 16384); }, MM16T(bh), {});
    }
    {  // c = NC-1
      const char* bp = lb + (((NC - 1) & 1) ? BUFSZ : 0);
      PH({ RD_B32(bp, 32768, bh); RD_A32(bp, 0); }, MM16T(bh), {});
      PH({ RD_A32(bp, 16384); }, MM16T(bh), {});
    }
  }

  // epilogue: 32x32 C/D layout col=lane&31, row=(g&3)+8*(g>>2)+4*(lane>>5)
#pragma unroll
  for (int mf = 0; mf < 4; ++mf)
#pragma unroll
    for (int nf = 0; nf < 2; ++nf)
#pragma unroll
      for (int g = 0; g < 16; ++g) {
        int r = rowA + (wr << 7) + (mf << 5) + (g & 3) + ((g >> 2) << 3) + (hi5 << 2);
        int c = colB + (wc << 6) + (nf << 5) + l31;
        float v = acc[mf][nf][g];
        if constexpr (MODE == 0) {
          store_split((us*)out0, (us*)out1, (size_t)r * 1024 + c, v);
        } else if constexpr (MODE == 1) {
          ((float*)out0)[((size_t)r * NB + bz) * NS + c] = v;  // align[t][b][s]
        } else if constexpr (MODE == 2) {
          store_split((us*)out0, (us*)out1, ((size_t)bz * 512 + r) * 1024 + c, v);
        } else {
          int bb = r >> 9, tt2 = r & 511;
          ((float*)out0)[((size_t)tt2 * NB + bb) * ND + c] = tanhf(v);  // attn[t][b][d]
        }
      }
}

// ---------------- launch ----------------
extern "C" void kernel_launch(void* const* d_in, const int* in_sizes, int n_in,
                              void* d_out, int out_size, void* d_ws, size_t ws_size,
                              hipStream_t stream) {
  (void)in_sizes; (void)n_in; (void)out_size; (void)ws_size;
  const float* inp = (const float*)d_in[0];   // [32][512][1024]
  const float* ctx = (const float*)d_in[1];   // [32][1024][1024]
  const float* Win = (const float*)d_in[2];   // [1024][1024] (e,d)
  const float* Wout = (const float*)d_in[3];  // [1024][2048] (d,f)
  float* out = (float*)d_out;

  char* w = (char*)d_ws;
  us* ctx_hi  = (us*)(w + 0);
  us* c_hi    = (us*)(w + 0);
  us* c_lo    = (us*)(w + 33554432);
  us* ctx_lo  = (us*)(w + 67108864);
  us* p_hi    = (us*)(w + 67108864);
  us* p_lo    = (us*)(w + 100663296);
  us* in_hi   = (us*)(w + 134217728);
  us* in_lo   = (us*)(w + 167772160);
  us* h_hi    = (us*)(w + 201326592);
  us* h_lo    = (us*)(w + 234881024);
  us* ctxT_lo = (us*)(w + 201326592);  // reuses h region after GEMM2
  us* win_hi  = (us*)(w + 268435456);
  us* win_lo  = (us*)(w + 270532608);
  us* wout_b  = (us*)(w + 272629760);

  us* ctxT_hi = (us*)d_out;            // attn region as scratch until GEMM4
  float* alignOut = out + 16777216;    // second half of d_out

  ga_split<<<2048, 256, 0, stream>>>(inp, in_hi, in_lo, 16777216L);
  ga_split<<<2048, 256, 0, stream>>>(ctx, ctx_hi, ctx_lo, 33554432L);
  ga_split<<<512, 256, 0, stream>>>(Win, win_hi, win_lo, 1048576L);
  ga_cvt<<<512, 256, 0, stream>>>(Wout, wout_b, 2097152L);

  // GEMM1: h = in @ W_in^T   (M=16384, N=1024, 3-term chunks)
  ga_gf<0><<<dim3(64, 4, 1), 512, 0, stream>>>(in_hi, in_lo, nullptr, nullptr,
                                               win_hi, win_lo, h_hi, h_lo, 0L, 0L);
  // GEMM2: align = h @ ctx^T (batched 32; M=512, N=1024) [XCD swz]
  ga_gf<1><<<dim3(256, 1, 1), 512, 0, stream>>>(h_hi, h_lo, nullptr, nullptr,
                                                ctx_hi, ctx_lo, alignOut, nullptr,
                                                524288L, 1048576L);
  // ctx transpose+split (overwrites h region -> must follow GEMM2; stream-ordered)
  ga_transpose_split<<<dim3(16, 16, 32), 256, 0, stream>>>(ctx, ctxT_hi, ctxT_lo);
  // softmax in-place + P split planes
  ga_softmax<<<16384, 256, 0, stream>>>(alignOut, p_hi, p_lo);
  // GEMM3: c = P @ ctx (via ctxT planes; batched) [XCD swz]
  ga_gf<2><<<dim3(256, 1, 1), 512, 0, stream>>>(p_hi, p_lo, nullptr, nullptr,
                                                ctxT_hi, ctxT_lo, c_hi, c_lo,
                                                524288L, 1048576L);
  // GEMM4: attn = tanh(concat[c,in] @ W_out^T) (2-term, 64 chunks)
  ga_gf<3><<<dim3(64, 4, 1), 512, 0, stream>>>(c_hi, c_lo, in_hi, in_lo,
                                               wout_b, nullptr, out, nullptr, 0L, 0L);
}

// Round 15
// 552.112 us; speedup vs baseline: 1.2414x; 1.0708x over previous
//
#include <hip/hip_runtime.h>
#include <hip/hip_bf16.h>

// GlobalAttention (general): B=32, T=512, S=1024, D=1024, f32 in/out.
// FINAL CONFIG (round-15 = revert to round-10 best, 554us):
// Split-bf16 GEMMs as K-SEGMENTED plain bf16 GEMMs (Markidis 3-term =
// [Ah|Ah|Al]x[Bh|Bl|Bh], K'=3072; GEMM4 4-seg K'=4096).
// Engine: 256x256 tile, BK=64, 8 waves (2Mx4N), 16x16x32 MFMA, LDS 128KB
// (2 buf x {A0,A1,B0,B1} 16KB halves), 1 barrier/phase, 8 phases / 2 tiles.
// A frags read IN-PHASE pre-MM (compiler counted-lgkm per use); B frags read
// ONE PHASE AHEAD (post-MM p4/p8). Stage slots (WAR-audited, round-9):
//   p1:A1(X+1) p2:B0(X+2) p3:B1(X+2) p4:A0(X+2)
//   p5:A1(X+2) p6:B0(X+3) p7:B1(X+3) p8:A0(X+3)
// XCD-aware block swizzle for the BATCHED GEMMs (MODE 1/2): 1D grid 256,
// xcd=i&7; j=i>>3; batch=xcd*4+(j&3); panel=j>>2 -> each XCD owns 4
// batches x 8 panels (FETCH 393->~100MB). GEMM1/4 keep 2D grid.
// 14-round summary: 3 engine families x 2 MFMA shapes x 2 occupancies all
// converge at 44-46% MfmaUtil; wins were m201-schedule (+15%) and XCD
// locality (+10%). 32x32 MFMA variants re-introduce 4-way LDS conflicts.

typedef short bf16x8 __attribute__((ext_vector_type(8)));
typedef float f32x4 __attribute__((ext_vector_type(4)));
typedef unsigned short us;

#define NB 32
#define NT_ 512
#define NS 1024
#define ND 1024

__device__ inline us f2bf(float x) {
  unsigned u = __float_as_uint(x);
  u += 0x7FFFu + ((u >> 16) & 1u);
  return (us)(u >> 16);
}
__device__ inline float bf2f(us h) { return __uint_as_float(((unsigned)h) << 16); }

__device__ inline void store_split(us* __restrict__ hi, us* __restrict__ lo, size_t idx, float v) {
  us h = f2bf(v);
  hi[idx] = h;
  lo[idx] = f2bf(v - bf2f(h));
}

// ---------------- elementwise split / convert ----------------
__global__ void ga_split(const float* __restrict__ src, us* __restrict__ hi,
                         us* __restrict__ lo, long n) {
  long i0 = ((long)blockIdx.x * blockDim.x + threadIdx.x) * 4;
  long stride = (long)gridDim.x * blockDim.x * 4;
  for (long i = i0; i < n; i += stride) {
    float4 v = *reinterpret_cast<const float4*>(src + i);
    ushort4 h, l;
    h.x = f2bf(v.x); l.x = f2bf(v.x - bf2f(h.x));
    h.y = f2bf(v.y); l.y = f2bf(v.y - bf2f(h.y));
    h.z = f2bf(v.z); l.z = f2bf(v.z - bf2f(h.z));
    h.w = f2bf(v.w); l.w = f2bf(v.w - bf2f(h.w));
    *reinterpret_cast<ushort4*>(hi + i) = h;
    *reinterpret_cast<ushort4*>(lo + i) = l;
  }
}

__global__ void ga_cvt(const float* __restrict__ src, us* __restrict__ dst, long n) {
  long i0 = ((long)blockIdx.x * blockDim.x + threadIdx.x) * 4;
  long stride = (long)gridDim.x * blockDim.x * 4;
  for (long i = i0; i < n; i += stride) {
    float4 v = *reinterpret_cast<const float4*>(src + i);
    ushort4 h;
    h.x = f2bf(v.x); h.y = f2bf(v.y); h.z = f2bf(v.z); h.w = f2bf(v.w);
    *reinterpret_cast<ushort4*>(dst + i) = h;
  }
}

// ---------------- ctx transpose+split: [B][S][D] f32 -> [B][D][S] bf16 hi/lo ----------------
__global__ void ga_transpose_split(const float* __restrict__ ctx, us* __restrict__ tHi,
                                   us* __restrict__ tLo) {
  __shared__ float tile[64][65];
  int s0 = blockIdx.x << 6, d0 = blockIdx.y << 6, b = blockIdx.z;
  const float* src = ctx + (size_t)b * NS * ND;
  int tid = threadIdx.x;
#pragma unroll
  for (int i = 0; i < 16; ++i) {
    int lin = (i << 8) + tid;
    int r = lin >> 6, c = lin & 63;
    tile[r][c] = src[(size_t)(s0 + r) * ND + d0 + c];
  }
  __syncthreads();
  us* oH = tHi + (size_t)b * ND * NS;
  us* oL = tLo + (size_t)b * ND * NS;
#pragma unroll
  for (int i = 0; i < 16; ++i) {
    int lin = (i << 8) + tid;
    int dr = lin >> 6, sc = lin & 63;
    float v = tile[sc][dr];
    size_t o = (size_t)(d0 + dr) * NS + s0 + sc;
    us h = f2bf(v);
    oH[o] = h;
    oL[o] = f2bf(v - bf2f(h));
  }
}

// ---------------- row softmax, in-place f32 + split planes ----------------
__global__ __launch_bounds__(256) void ga_softmax(float* __restrict__ al,
                                                  us* __restrict__ pHi, us* __restrict__ pLo) {
  int row = blockIdx.x;  // t*32 + b
  int tid = threadIdx.x;
  float* p = al + (size_t)row * NS;
  float4 v = *reinterpret_cast<const float4*>(p + (tid << 2));
  float m = fmaxf(fmaxf(v.x, v.y), fmaxf(v.z, v.w));
#pragma unroll
  for (int off = 32; off; off >>= 1) m = fmaxf(m, __shfl_xor(m, off));
  __shared__ float rmax[4], rsum[4];
  int wv = tid >> 6, ln = tid & 63;
  if (ln == 0) rmax[wv] = m;
  __syncthreads();
  m = fmaxf(fmaxf(rmax[0], rmax[1]), fmaxf(rmax[2], rmax[3]));
  float4 e;
  e.x = __expf(v.x - m); e.y = __expf(v.y - m);
  e.z = __expf(v.z - m); e.w = __expf(v.w - m);
  float s = e.x + e.y + e.z + e.w;
#pragma unroll
  for (int off = 32; off; off >>= 1) s += __shfl_xor(s, off);
  if (ln == 0) rsum[wv] = s;
  __syncthreads();
  s = rsum[0] + rsum[1] + rsum[2] + rsum[3];
  float inv = 1.0f / s;
  e.x *= inv; e.y *= inv; e.z *= inv; e.w *= inv;
  *reinterpret_cast<float4*>(p + (tid << 2)) = e;
  int t = row >> 5, b = row & 31;
  size_t o = ((size_t)b * NT_ + t) * NS + (tid << 2);
  ushort4 h, l;
  h.x = f2bf(e.x); l.x = f2bf(e.x - bf2f(h.x));
  h.y = f2bf(e.y); l.y = f2bf(e.y - bf2f(h.y));
  h.z = f2bf(e.z); l.z = f2bf(e.z - bf2f(h.z));
  h.w = f2bf(e.w); l.w = f2bf(e.w - bf2f(h.w));
  *reinterpret_cast<ushort4*>(pHi + o) = h;
  *reinterpret_cast<ushort4*>(pLo + o) = l;
}

// ---------------- K-segmented bf16 GEMM, compiler-waited overlap engine ----------------
__device__ inline void gload16(const us* g, void* l) {
  __builtin_amdgcn_global_load_lds((const __attribute__((address_space(1))) unsigned int*)g,
                                   (__attribute__((address_space(3))) unsigned int*)l, 16, 0, 0);
}

__device__ inline f32x4 mfma16(bf16x8 a, bf16x8 b, f32x4 c) {
  return __builtin_amdgcn_mfma_f32_16x16x32_bf16(a, b, c, 0, 0, 0);
}

#define VM4 asm volatile("s_waitcnt vmcnt(4)" ::: "memory")
#define VM0 asm volatile("s_waitcnt vmcnt(0)" ::: "memory")

#define STG_A(T, H) do {                                                           \
    int s3_ = (T) >> 4;                                                            \
    const us* ga_ = (MODE == 3)                                                    \
        ? ((s3_ == 0) ? pA0 : (s3_ == 1) ? pA1 : (s3_ == 2) ? pA2 : pA3)           \
        : ((s3_ == 2) ? pA1 : pA0);                                                \
    const us* g_ = ga_ + (((T) & 15) << 6) + ((H) ? 131072 : 0) + aOff0;           \
    char* d_ = lb + (((T) & 1) << 16) + ((H) << 14) + (tid << 4);                  \
    gload16(g_, d_);                                                               \
    gload16(g_ + 65536, d_ + 8192);                                                \
  } while (0)

#define STG_B(T, H) do {                                                           \
    int s3_ = (T) >> 4;                                                            \
    const us* gb_ = (MODE == 3) ? ((s3_ >= 2) ? pB2 : pB0)                         \
                                : ((s3_ == 1) ? pB1 : pB0);                        \
    const us* g_ = gb_ + (((T) & 15) << 6) + ((H) ? (LDB << 7) : 0) + bOff0;       \
    char* d_ = lb + (((T) & 1) << 16) + 32768 + ((H) << 14) + (tid << 4);          \
    gload16(g_, d_);                                                               \
    gload16(g_ + (LDB << 6), d_ + 8192);                                           \
  } while (0)

#define RD_A(BP, ARR, QM) do {                                                     \
    const char* p_ = (BP) + aRd + ((QM) << 13);                                    \
    _Pragma("unroll") for (int m_ = 0; m_ < 4; ++m_) {                             \
      ARR[m_][0] = *(const bf16x8*)(p_ + (m_ << 11) + colx0);                      \
      ARR[m_][1] = *(const bf16x8*)(p_ + (m_ << 11) + colx1);                      \
    }                                                                              \
  } while (0)

#define RD_B(BP, ARR, QN) do {                                                     \
    const char* p_ = (BP) + bRd + ((QN) << 12);                                    \
    _Pragma("unroll") for (int n_ = 0; n_ < 2; ++n_) {                             \
      ARR[n_][0] = *(const bf16x8*)(p_ + (n_ << 11) + colx0);                      \
      ARR[n_][1] = *(const bf16x8*)(p_ + (n_ << 11) + colx1);                      \
    }                                                                              \
  } while (0)

// m-outer so the first MFMA unlocks after A[0]'s 2 reads (B pre-read earlier)
#define MM(QM, QN, AA, BB)                                                         \
  _Pragma("unroll") for (int m_ = 0; m_ < 4; ++m_)                                 \
  _Pragma("unroll") for (int ks_ = 0; ks_ < 2; ++ks_)                              \
  _Pragma("unroll") for (int n_ = 0; n_ < 2; ++n_)                                 \
    acc[(QM) * 4 + m_][(QN) * 2 + n_] =                                            \
        mfma16(AA[m_][ks_], BB[n_][ks_], acc[(QM) * 4 + m_][(QN) * 2 + n_])

#define PH(RDS, MMQ, POST) do {                                                    \
    __builtin_amdgcn_s_barrier();                                                  \
    RDS;                                                                           \
    __builtin_amdgcn_s_setprio(1);                                                 \
    MMQ;                                                                           \
    __builtin_amdgcn_s_setprio(0);                                                 \
    POST;                                                                          \
  } while (0)

// MODE 0: GEMM1 h=in*W_in^T, K'=3072 -> h planes.      grid(64,4,1)
// MODE 1: GEMM2 align=h*ctx^T, K'=3072 -> f32 align.   grid(256) XCD-swz
// MODE 2: GEMM3 c=P*ctxT^T, K'=3072 -> c planes.       grid(256) XCD-swz
// MODE 3: GEMM4 tanh(concat*W_out^T), K'=4096 -> out.  grid(64,4,1)
template <int MODE>
__global__ __launch_bounds__(512, 1) void ga_gb(
    const us* __restrict__ Ahi, const us* __restrict__ Alo,
    const us* __restrict__ A2hi, const us* __restrict__ A2lo,
    const us* __restrict__ Bhi, const us* __restrict__ Blo,
    void* __restrict__ out0, void* __restrict__ out1,
    long astride, long bstride) {
  constexpr int LDB = (MODE == 3) ? 2048 : 1024;
  constexpr int NT = (MODE == 3) ? 64 : 48;
  constexpr int NIT = NT >> 1;
  __shared__ __align__(16) char lds[131072];
  char* lb = lds;
  const int tid = threadIdx.x;
  const int lane = tid & 63;
  const int fr = lane & 15;
  const int wv = tid >> 6;
  const int wr = wv >> 2, wc = wv & 3;  // 2M x 4N waves, per-wave 128x64

  // block decode: XCD-aware for batched modes (each XCD owns 4 batches)
  int rowA, colB, bz;
  if constexpr (MODE == 1 || MODE == 2) {
    const int bi = blockIdx.x;            // 0..255, XCD ~= bi & 7
    const int j = bi >> 3;                // 0..31 within XCD
    bz = ((bi & 7) << 2) + (j & 3);       // 4 batches per XCD
    const int panel = j >> 2;             // 0..7 = 2 rowA x 4 colB
    rowA = (panel & 1) << 8;
    colB = (panel >> 1) << 8;
  } else {
    rowA = blockIdx.x << 8;
    colB = blockIdx.y << 8;
    bz = blockIdx.z;
  }

  // segment base pointers (uniform -> SGPR)
  const us* pA0 = Ahi + (size_t)bz * astride + (size_t)rowA * 1024;
  const us* pA1 = Alo + (size_t)bz * astride + (size_t)rowA * 1024;
  const us* pA2 = (MODE == 3) ? A2hi + (size_t)rowA * 1024 : nullptr;
  const us* pA3 = (MODE == 3) ? A2lo + (size_t)rowA * 1024 : nullptr;
  const us* pB0 = Bhi + (size_t)bz * bstride + (size_t)colB * LDB;
  const us* pB1 = (MODE == 3) ? nullptr : Blo + (size_t)bz * bstride + (size_t)colB * LDB;
  const us* pB2 = (MODE == 3) ? pB0 + 1024 : nullptr;

  // staging geometry (pre-swizzled global source col, linear LDS dest)
  const int arow = tid >> 3;
  const int swe = ((tid & 7) ^ (arow & 7)) << 3;
  const int aOff0 = arow * 1024 + swe;
  const int bOff0 = arow * LDB + swe;

  // frag-read geometry (swizzled)
  const int l16 = ((lane >> 4) & 3) << 4;
  const int colx0 = l16 ^ ((fr & 7) << 4);
  const int colx1 = colx0 ^ 64;
  const int aRd = (wr << 14) + (fr << 7);
  const int bRd = 32768 + ((wc >> 1) << 14) + ((wc & 1) << 13) + (fr << 7);
  const char* BUF0 = lb;
  const char* BUF1 = lb + 65536;

  bf16x8 a4[4][2], b0[2][2], b1[2][2];
  f32x4 zero = {0.f, 0.f, 0.f, 0.f};
  f32x4 acc[8][4];
#pragma unroll
  for (int i = 0; i < 8; ++i)
#pragma unroll
    for (int k = 0; k < 4; ++k) acc[i][k] = zero;

  // prologue: stage tile0 full + tile1.{B0,B1,A0} (14 loads); drain all;
  // barrier publishes; pre-read tile0's B fragments.
  STG_B(0, 0); STG_B(0, 1); STG_A(0, 0); STG_A(0, 1);
  STG_B(1, 0); STG_B(1, 1); STG_A(1, 0);
  VM0;
  __builtin_amdgcn_s_barrier();
  RD_B(BUF0, b0, 0); RD_B(BUF0, b1, 1);

  for (int i = 0; i < NIT - 1; ++i) {
    const int X = i << 1;
    PH(RD_A(BUF0, a4, 0), MM(0, 0, a4, b0), { STG_A(X + 1, 1); VM4; });
    PH(,                  MM(0, 1, a4, b1), { STG_B(X + 2, 0); VM4; });
    PH(RD_A(BUF0, a4, 1), MM(1, 0, a4, b0), { STG_B(X + 2, 1); VM4; });
    PH(,                  MM(1, 1, a4, b1),
       { RD_B(BUF1, b0, 0); RD_B(BUF1, b1, 1); STG_A(X + 2, 0); VM4; });
    PH(RD_A(BUF1, a4, 0), MM(0, 0, a4, b0), { STG_A(X + 2, 1); VM4; });
    PH(,                  MM(0, 1, a4, b1), { STG_B(X + 3, 0); VM4; });
    PH(RD_A(BUF1, a4, 1), MM(1, 0, a4, b0), { STG_B(X + 3, 1); VM4; });
    PH(,                  MM(1, 1, a4, b1),
       { RD_B(BUF0, b0, 0); RD_B(BUF0, b1, 1); STG_A(X + 3, 0); VM4; });
  }
  // peeled last pair (tiles NT-2 in BUF0, NT-1 in BUF1): stage only
  // A1(NT-1)@p1; VM0@p3-post drains it, barrier_p4 publishes before the
  // p4 pre-reads and the p5/p7 A reads of BUF1.
  PH(RD_A(BUF0, a4, 0), MM(0, 0, a4, b0), { STG_A(NT - 1, 1); VM4; });
  PH(,                  MM(0, 1, a4, b1), {});
  PH(RD_A(BUF0, a4, 1), MM(1, 0, a4, b0), { VM0; });
  PH(,                  MM(1, 1, a4, b1),
     { RD_B(BUF1, b0, 0); RD_B(BUF1, b1, 1); });
  PH(RD_A(BUF1, a4, 0), MM(0, 0, a4, b0), {});
  PH(,                  MM(0, 1, a4, b1), {});
  PH(RD_A(BUF1, a4, 1), MM(1, 0, a4, b0), {});
  PH(,                  MM(1, 1, a4, b1), {});

  // epilogue: C/D layout col=lane&15, row=(lane>>4)*4+j
#pragma unroll
  for (int mf = 0; mf < 8; ++mf)
#pragma unroll
    for (int nf = 0; nf < 4; ++nf)
#pragma unroll
      for (int j = 0; j < 4; ++j) {
        int r = rowA + (wr << 7) + (mf << 4) + (((lane >> 4) & 3) << 2) + j;
        int c = colB + (wc << 6) + (nf << 4) + fr;
        float v = acc[mf][nf][j];
        if constexpr (MODE == 0) {
          store_split((us*)out0, (us*)out1, (size_t)r * 1024 + c, v);
        } else if constexpr (MODE == 1) {
          ((float*)out0)[((size_t)r * NB + bz) * NS + c] = v;  // align[t][b][s]
        } else if constexpr (MODE == 2) {
          store_split((us*)out0, (us*)out1, ((size_t)bz * 512 + r) * 1024 + c, v);
        } else {
          int bb = r >> 9, tt2 = r & 511;
          ((float*)out0)[((size_t)tt2 * NB + bb) * ND + c] = tanhf(v);  // attn[t][b][d]
        }
      }
}

// ---------------- launch ----------------
extern "C" void kernel_launch(void* const* d_in, const int* in_sizes, int n_in,
                              void* d_out, int out_size, void* d_ws, size_t ws_size,
                              hipStream_t stream) {
  (void)in_sizes; (void)n_in; (void)out_size; (void)ws_size;
  const float* inp = (const float*)d_in[0];   // [32][512][1024]
  const float* ctx = (const float*)d_in[1];   // [32][1024][1024]
  const float* Win = (const float*)d_in[2];   // [1024][1024] (e,d)
  const float* Wout = (const float*)d_in[3];  // [1024][2048] (d,f)
  float* out = (float*)d_out;

  char* w = (char*)d_ws;
  us* ctx_hi  = (us*)(w + 0);
  us* c_hi    = (us*)(w + 0);
  us* c_lo    = (us*)(w + 33554432);
  us* ctx_lo  = (us*)(w + 67108864);
  us* p_hi    = (us*)(w + 67108864);
  us* p_lo    = (us*)(w + 100663296);
  us* in_hi   = (us*)(w + 134217728);
  us* in_lo   = (us*)(w + 167772160);
  us* h_hi    = (us*)(w + 201326592);
  us* h_lo    = (us*)(w + 234881024);
  us* ctxT_lo = (us*)(w + 201326592);  // reuses h region after GEMM2
  us* win_hi  = (us*)(w + 268435456);
  us* win_lo  = (us*)(w + 270532608);
  us* wout_b  = (us*)(w + 272629760);

  us* ctxT_hi = (us*)d_out;            // attn region as scratch until GEMM4
  float* alignOut = out + 16777216;    // second half of d_out

  ga_split<<<2048, 256, 0, stream>>>(inp, in_hi, in_lo, 16777216L);
  ga_split<<<2048, 256, 0, stream>>>(ctx, ctx_hi, ctx_lo, 33554432L);
  ga_split<<<512, 256, 0, stream>>>(Win, win_hi, win_lo, 1048576L);
  ga_cvt<<<512, 256, 0, stream>>>(Wout, wout_b, 2097152L);

  // GEMM1: h = in @ W_in^T   (M=16384, N=1024, K'=3072)
  ga_gb<0><<<dim3(64, 4, 1), 512, 0, stream>>>(in_hi, in_lo, nullptr, nullptr,
                                               win_hi, win_lo, h_hi, h_lo, 0L, 0L);
  // GEMM2: align = h @ ctx^T (batched 32; M=512, N=1024, K'=3072) [XCD swz]
  ga_gb<1><<<dim3(256, 1, 1), 512, 0, stream>>>(h_hi, h_lo, nullptr, nullptr,
                                                ctx_hi, ctx_lo, alignOut, nullptr,
                                                524288L, 1048576L);
  // ctx transpose+split (overwrites h region -> must follow GEMM2; stream-ordered)
  ga_transpose_split<<<dim3(16, 16, 32), 256, 0, stream>>>(ctx, ctxT_hi, ctxT_lo);
  // softmax in-place + P split planes
  ga_softmax<<<16384, 256, 0, stream>>>(alignOut, p_hi, p_lo);
  // GEMM3: c = P @ ctx (via ctxT planes; batched; M=512, N=1024, K'=3072) [XCD swz]
  ga_gb<2><<<dim3(256, 1, 1), 512, 0, stream>>>(p_hi, p_lo, nullptr, nullptr,
                                                ctxT_hi, ctxT_lo, c_hi, c_lo,
                                                524288L, 1048576L);
  // GEMM4: attn = tanh(concat[c,in] @ W_out^T) (M=16384, N=1024, K'=4096)
  ga_gb<3><<<dim3(64, 4, 1), 512, 0, stream>>>(c_hi, c_lo, in_hi, in_lo,
                                               wout_b, nullptr, out, nullptr, 0L, 0L);
}